// Round 6
// baseline (292.163 us; speedup 1.0000x reference)
//
#include <hip/hip_runtime.h>
#include <math.h>

#define NMAX 4096
#define N4   (NMAX/4)

// n assumed multiple of 16 (reference: N=4096).

constexpr float RADIUS       = 0.1f;
constexpr float DT           = 1.0f / 60.0f;
constexpr float MAX_VEL      = 3.0f;               // 0.5*0.1/DT
constexpr float VISCOSITY    = 60.0f;
constexpr float DENSITY_REST = 17510.1f;
constexpr float STIFFNESS    = 2.99e-11f;
constexpr float EPS          = 1e-8f;
constexpr float SPIKY_C      = (float)(15.0 / (3.14159265358979323846 * 1e-6)); // 15/(pi*R^6)

__device__ __forceinline__ float elem(const float4& v, int c) {
    return reinterpret_cast<const float*>(&v)[c];
}

// Distributed grid barrier: per-block flags (no contention) + single release word.
// Sense k is monotone 1..6 within a call; ws poison 0xAA reads as negative int -> '< k' safe.
__device__ __forceinline__ void grid_barrier(int* __restrict__ flags, int* __restrict__ release,
                                             int k, int nblocks) {
    __syncthreads();
    if (threadIdx.x == 0) {
        __threadfence();   // device-scope release of prior global writes
        __hip_atomic_store(&flags[blockIdx.x], k, __ATOMIC_RELEASE, __HIP_MEMORY_SCOPE_AGENT);
    }
    if (blockIdx.x == 0) {
        for (int t = threadIdx.x; t < nblocks; t += blockDim.x) {
            while (__hip_atomic_load(&flags[t], __ATOMIC_ACQUIRE, __HIP_MEMORY_SCOPE_AGENT) < k) {}
        }
        __syncthreads();
        if (threadIdx.x == 0)
            __hip_atomic_store(release, k, __ATOMIC_RELEASE, __HIP_MEMORY_SCOPE_AGENT);
    }
    if (threadIdx.x == 0) {
        while (__hip_atomic_load(release, __ATOMIC_ACQUIRE, __HIP_MEMORY_SCOPE_AGENT) < k) {}
    }
    __syncthreads();
}

// Recompute predicted positions for the whole system into LDS (SoA float4).
__device__ __forceinline__ void predict_to_lds(const float4* __restrict__ locs4,
                                               const float4* __restrict__ vel4,
                                               float4* sx, float4* sy, float4* sz,
                                               int n4, int tid, int nthreads) {
    for (int g = tid; g < n4; g += nthreads) {
        float lo[12], ve[12];
        *(float4*)&lo[0] = locs4[3*g];   *(float4*)&lo[4] = locs4[3*g+1]; *(float4*)&lo[8] = locs4[3*g+2];
        *(float4*)&ve[0] = vel4[3*g];    *(float4*)&ve[4] = vel4[3*g+1];  *(float4*)&ve[8] = vel4[3*g+2];
        float X[4], Y[4], Z[4];
#pragma unroll
        for (int p = 0; p < 4; ++p) {
            float vx = ve[3*p], vy = ve[3*p+1] - 9.8f * DT, vz = ve[3*p+2];
            float vv = sqrtf(vx*vx + vy*vy + vz*vz);
            float s  = fminf(MAX_VEL / (vv + 1e-4f), 1.0f);
            X[p] = lo[3*p]   + DT * vx * s;
            Y[p] = lo[3*p+1] + DT * vy * s;
            Z[p] = lo[3*p+2] + DT * vz * s;
        }
        sx[g] = make_float4(X[0], X[1], X[2], X[3]);
        sy[g] = make_float4(Y[0], Y[1], Y[2], Y[3]);
        sz[g] = make_float4(Z[0], Z[1], Z[2], Z[3]);
    }
}

// rho body (2 particles/wave): writes pre-scaled L = -3C*lam for i0, i0+1 to global.
__device__ __forceinline__ void rho_body2(const float4* sx, const float4* sy, const float4* sz,
                                          float* __restrict__ lam, int n4, int i0, int lane) {
    const float* fx = (const float*)sx; const float* fy = (const float*)sy; const float* fz = (const float*)sz;
    const float xi0 = fx[i0],   yi0 = fy[i0],   zi0 = fz[i0];
    const float xi1 = fx[i0+1], yi1 = fy[i0+1], zi1 = fz[i0+1];
    float S0 = 0.f, S1 = 0.f;
    for (int k = lane; k < n4; k += 64) {
        float4 X = sx[k], Y = sy[k], Z = sz[k];
#pragma unroll
        for (int c = 0; c < 4; ++c) {
            float xj = elem(X,c), yj = elem(Y,c), zj = elem(Z,c);
            {
                float dx = xi0-xj, dy = yi0-yj, dz = zi0-zj;
                float d2 = fmaf(dx,dx,EPS); d2 = fmaf(dy,dy,d2); d2 = fmaf(dz,dz,d2);
                float t  = fmaxf(RADIUS - __builtin_amdgcn_sqrtf(d2), 0.f);
                S0 = fmaf(t*t, t, S0);
            }
            {
                float dx = xi1-xj, dy = yi1-yj, dz = zi1-zj;
                float d2 = fmaf(dx,dx,EPS); d2 = fmaf(dy,dy,d2); d2 = fmaf(dz,dz,d2);
                float t  = fmaxf(RADIUS - __builtin_amdgcn_sqrtf(d2), 0.f);
                S1 = fmaf(t*t, t, S1);
            }
        }
    }
    for (int off = 32; off > 0; off >>= 1) {
        S0 += __shfl_down(S0, off);
        S1 += __shfl_down(S1, off);
    }
    if (lane == 0) {
        const float ts  = RADIUS - __builtin_amdgcn_sqrtf(EPS);  // exact self-term
        const float TS3 = ts*ts*ts;
        const float k3  = 3.f * SPIKY_C * STIFFNESS;             // L = -3C*lam
        lam[i0]   = k3 * (SPIKY_C * (S0 - TS3) - DENSITY_REST);
        lam[i0+1] = k3 * (SPIKY_C * (S1 - TS3) - DENSITY_REST);
    }
}

// delta body (2 particles/wave): writes new positions (and optional final outputs) to global.
__device__ __forceinline__ void delta_body2(const float4* sx, const float4* sy, const float4* sz,
                                            const float4* sl,
                                            float* __restrict__ qx, float* __restrict__ qy, float* __restrict__ qz,
                                            const float* __restrict__ locs, float* __restrict__ out_pred,
                                            float* __restrict__ vnx, float* __restrict__ vny, float* __restrict__ vnz,
                                            int n4, int i0, int lane, bool final_iter) {
    const float* fx = (const float*)sx; const float* fy = (const float*)sy;
    const float* fz = (const float*)sz; const float* fl = (const float*)sl;
    const float xi0 = fx[i0],   yi0 = fy[i0],   zi0 = fz[i0],   L0 = fl[i0];
    const float xi1 = fx[i0+1], yi1 = fy[i0+1], zi1 = fz[i0+1], L1 = fl[i0+1];
    float ax0=0.f, ay0=0.f, az0=0.f, ax1=0.f, ay1=0.f, az1=0.f;
    for (int k = lane; k < n4; k += 64) {
        float4 X = sx[k], Y = sy[k], Z = sz[k], L = sl[k];
#pragma unroll
        for (int c = 0; c < 4; ++c) {
            float xj = elem(X,c), yj = elem(Y,c), zj = elem(Z,c), Lj = elem(L,c);
            {
                float dx = xi0-xj, dy = yi0-yj, dz = zi0-zj;
                float d2 = fmaf(dx,dx,EPS); d2 = fmaf(dy,dy,d2); d2 = fmaf(dz,dz,d2);
                float rinv = __builtin_amdgcn_rsqf(d2);
                float t  = fmaxf(RADIUS - d2*rinv, 0.f);
                float cf = (L0 + Lj) * (t*t) * rinv;
                ax0 = fmaf(cf, dx, ax0); ay0 = fmaf(cf, dy, ay0); az0 = fmaf(cf, dz, az0);
            }
            {
                float dx = xi1-xj, dy = yi1-yj, dz = zi1-zj;
                float d2 = fmaf(dx,dx,EPS); d2 = fmaf(dy,dy,d2); d2 = fmaf(dz,dz,d2);
                float rinv = __builtin_amdgcn_rsqf(d2);
                float t  = fmaxf(RADIUS - d2*rinv, 0.f);
                float cf = (L1 + Lj) * (t*t) * rinv;
                ax1 = fmaf(cf, dx, ax1); ay1 = fmaf(cf, dy, ay1); az1 = fmaf(cf, dz, az1);
            }
        }
    }
    for (int off = 32; off > 0; off >>= 1) {
        ax0 += __shfl_down(ax0, off); ay0 += __shfl_down(ay0, off); az0 += __shfl_down(az0, off);
        ax1 += __shfl_down(ax1, off); ay1 += __shfl_down(ay1, off); az1 += __shfl_down(az1, off);
    }
    if (lane == 0) {
        float nx0 = xi0+ax0, ny0 = yi0+ay0, nz0 = zi0+az0;
        float nx1 = xi1+ax1, ny1 = yi1+ay1, nz1 = zi1+az1;
        qx[i0] = nx0; qy[i0] = ny0; qz[i0] = nz0;
        qx[i0+1] = nx1; qy[i0+1] = ny1; qz[i0+1] = nz1;
        if (final_iter) {
#pragma unroll
            for (int u = 0; u < 2; ++u) {
                int i = i0 + u;
                float nx_ = u ? nx1 : nx0, ny_ = u ? ny1 : ny0, nz_ = u ? nz1 : nz0;
                out_pred[3*i+0] = nx_; out_pred[3*i+1] = ny_; out_pred[3*i+2] = nz_;
                vnx[i] = (nx_ - locs[3*i+0]) * (1.0f/DT);
                vny[i] = (ny_ - locs[3*i+1]) * (1.0f/DT);
                vnz[i] = (nz_ - locs[3*i+2]) * (1.0f/DT);
            }
        }
    }
}

// One cooperative kernel, hand-rolled barriers. 256 blocks x 512 thr, 64 KB LDS, 2 blocks/CU.
__global__ __launch_bounds__(512, 4) void k_fused(
        const float* __restrict__ locs, const float* __restrict__ vel,
        float* __restrict__ px, float* __restrict__ py, float* __restrict__ pz,
        float* __restrict__ lam,
        float* __restrict__ vnx, float* __restrict__ vny, float* __restrict__ vnz,
        int* __restrict__ flags, int* __restrict__ release,
        float* __restrict__ out, int n) {
    __shared__ float4 smem[4 * N4];   // 64 KB
    float4* sx = smem; float4* sy = smem + N4; float4* sz = smem + 2*N4; float4* sl = smem + 3*N4;
    const int tid = threadIdx.x;
    const int wave = tid >> 6, lane = tid & 63;
    const int i0 = blockIdx.x * 16 + wave * 2;
    const int n4 = n >> 2;
    const int nblocks = gridDim.x;

    // ---- 3 solver iterations; predict folded into iteration 0's staging ----
    for (int it = 0; it < 3; ++it) {
        if (it == 0) {
            predict_to_lds((const float4*)locs, (const float4*)vel, sx, sy, sz, n4, tid, 512);
        } else {
            for (int idx = tid; idx < n4; idx += 512) {
                sx[idx] = ((const float4*)px)[idx];
                sy[idx] = ((const float4*)py)[idx];
                sz[idx] = ((const float4*)pz)[idx];
            }
        }
        __syncthreads();
        rho_body2(sx, sy, sz, lam, n4, i0, lane);
        grid_barrier(flags, release, 2*it + 1, nblocks);       // lam ready
        for (int idx = tid; idx < n4; idx += 512) sl[idx] = ((const float4*)lam)[idx];
        __syncthreads();
        delta_body2(sx, sy, sz, sl, px, py, pz, locs, out, vnx, vny, vnz,
                    n4, i0, lane, it == 2);
        grid_barrier(flags, release, 2*it + 2, nblocks);       // new positions ready
    }

    // ---- XSPH viscosity: 2 chunks of 48 KB staged into smem ----
    const int n8 = n >> 3;
    float4* cx  = smem;        float4* cy  = smem + n8;     float4* cz  = smem + 2*n8;
    float4* cvx = smem + 3*n8; float4* cvy = smem + 4*n8;   float4* cvz = smem + 5*n8;
    const float xi0 = px[i0],  yi0 = py[i0],  zi0 = pz[i0];
    const float xi1 = px[i0+1], yi1 = py[i0+1], zi1 = pz[i0+1];
    const float vix0 = vnx[i0],   viy0 = vny[i0],   viz0 = vnz[i0];
    const float vix1 = vnx[i0+1], viy1 = vny[i0+1], viz1 = vnz[i0+1];
    float ws0=0.f, ax0=0.f, ay0=0.f, az0=0.f;
    float ws1=0.f, ax1=0.f, ay1=0.f, az1=0.f;
    for (int ch = 0; ch < 2; ++ch) {
        __syncthreads();
        for (int idx = tid; idx < n8; idx += 512) {
            cx[idx]  = ((const float4*)px)[ch*n8+idx];
            cy[idx]  = ((const float4*)py)[ch*n8+idx];
            cz[idx]  = ((const float4*)pz)[ch*n8+idx];
            cvx[idx] = ((const float4*)vnx)[ch*n8+idx];
            cvy[idx] = ((const float4*)vny)[ch*n8+idx];
            cvz[idx] = ((const float4*)vnz)[ch*n8+idx];
        }
        __syncthreads();
        for (int k = lane; k < n8; k += 64) {
            float4 X = cx[k], Y = cy[k], Z = cz[k], VX = cvx[k], VY = cvy[k], VZ = cvz[k];
#pragma unroll
            for (int c = 0; c < 4; ++c) {
                float xj = elem(X,c), yj = elem(Y,c), zj = elem(Z,c);
                float vxj = elem(VX,c), vyj = elem(VY,c), vzj = elem(VZ,c);
                {
                    float dx = xi0-xj, dy = yi0-yj, dz = zi0-zj;
                    float d2 = fmaf(dx,dx,EPS); d2 = fmaf(dy,dy,d2); d2 = fmaf(dz,dz,d2);
                    float t  = fmaxf(RADIUS - __builtin_amdgcn_sqrtf(d2), 0.f);
                    float w  = t*t*t;
                    ws0 += w;
                    ax0 = fmaf(w, vxj, ax0); ay0 = fmaf(w, vyj, ay0); az0 = fmaf(w, vzj, az0);
                }
                {
                    float dx = xi1-xj, dy = yi1-yj, dz = zi1-zj;
                    float d2 = fmaf(dx,dx,EPS); d2 = fmaf(dy,dy,d2); d2 = fmaf(dz,dz,d2);
                    float t  = fmaxf(RADIUS - __builtin_amdgcn_sqrtf(d2), 0.f);
                    float w  = t*t*t;
                    ws1 += w;
                    ax1 = fmaf(w, vxj, ax1); ay1 = fmaf(w, vyj, ay1); az1 = fmaf(w, vzj, az1);
                }
            }
        }
    }
    for (int off = 32; off > 0; off >>= 1) {
        ws0 += __shfl_down(ws0, off); ax0 += __shfl_down(ax0, off);
        ay0 += __shfl_down(ay0, off); az0 += __shfl_down(az0, off);
        ws1 += __shfl_down(ws1, off); ax1 += __shfl_down(ax1, off);
        ay1 += __shfl_down(ay1, off); az1 += __shfl_down(az1, off);
    }
    if (lane == 0) {
        constexpr float K = VISCOSITY * DT / DENSITY_REST;
        const float KC = K * SPIKY_C;   // C folded here
#pragma unroll
        for (int u = 0; u < 2; ++u) {
            int i = i0 + u;
            float vix = (u ? vix1 : vix0), viy = (u ? viy1 : viy0), viz = (u ? viz1 : viz0);
            float sw  = (u ? ws1 : ws0);
            float sax = (u ? ax1 : ax0), say = (u ? ay1 : ay0), saz = (u ? az1 : az0);
            float nvx = vix + KC * (sax - sw * vix);
            float nvy = viy + KC * (say - sw * viy);
            float nvz = viz + KC * (saz - sw * viz);
            float vv = sqrtf(nvx*nvx + nvy*nvy + nvz*nvz);
            float s  = fminf(MAX_VEL / (vv + 1e-4f), 1.0f);
            out[3*n + 3*i + 0] = nvx * s;
            out[3*n + 3*i + 1] = nvy * s;
            out[3*n + 3*i + 2] = nvz * s;
        }
    }
}

extern "C" void kernel_launch(void* const* d_in, const int* in_sizes, int n_in,
                              void* d_out, int out_size, void* d_ws, size_t ws_size,
                              hipStream_t stream) {
    const float* locs = (const float*)d_in[0];
    const float* vel  = (const float*)d_in[1];
    float* out = (float*)d_out;
    int n = in_sizes[0] / 3;

    float* w = (float*)d_ws;
    float* px  = w;        float* py  = px + n;   float* pz  = py + n;
    float* lam = pz + n;
    float* vnx = lam + n;  float* vny = vnx + n;  float* vnz = vny + n;
    int* flags   = (int*)(vnz + n);
    int* release = flags + (n / 16);

    int nb = n / 16;   // 256 blocks: 8 waves/block, 2 particles/wave; 2 blocks/CU co-resident

    void* args[] = { (void*)&locs, (void*)&vel, (void*)&px, (void*)&py, (void*)&pz,
                     (void*)&lam, (void*)&vnx, (void*)&vny, (void*)&vnz,
                     (void*)&flags, (void*)&release, (void*)&out, (void*)&n };
    hipLaunchCooperativeKernel((const void*)k_fused, dim3(nb), dim3(512), args, 0, stream);
}

// Round 7
// 191.171 us; speedup vs baseline: 1.5283x; 1.5283x over previous
//
#include <hip/hip_runtime.h>
#include <math.h>

#define NMAX 4096
#define N4   (NMAX/4)

// n assumed multiple of 16 (reference: N=4096).

constexpr float RADIUS       = 0.1f;
constexpr float DT           = 1.0f / 60.0f;
constexpr float MAX_VEL      = 3.0f;               // 0.5*0.1/DT
constexpr float VISCOSITY    = 60.0f;
constexpr float DENSITY_REST = 17510.1f;
constexpr float STIFFNESS    = 2.99e-11f;
constexpr float EPS          = 1e-8f;
constexpr float SPIKY_C      = (float)(15.0 / (3.14159265358979323846 * 1e-6)); // 15/(pi*R^6)

#define FLAG_STRIDE 16   // ints; 64 B between flags -> no false sharing

__device__ __forceinline__ float elem(const float4& v, int c) {
    return reinterpret_cast<const float*>(&v)[c];
}

// Distributed grid barrier, relaxed polls + per-block fences.
// Sense k monotone 1..6 per launch; ws poison 0xAAAAAAAA < k (signed) -> no init needed.
__device__ __forceinline__ void grid_barrier(int* __restrict__ flags, int k, int nblocks) {
    __syncthreads();
    if (threadIdx.x == 0) {
        __threadfence();   // one release: drain + writeback prior global writes
        __hip_atomic_store(&flags[blockIdx.x * FLAG_STRIDE], k,
                           __ATOMIC_RELAXED, __HIP_MEMORY_SCOPE_AGENT);
    }
    // every block polls all flags (threads 0..nblocks-1, one flag each), relaxed
    for (int t = threadIdx.x; t < nblocks; t += (int)blockDim.x) {
        while (__hip_atomic_load(&flags[t * FLAG_STRIDE],
                                 __ATOMIC_RELAXED, __HIP_MEMORY_SCOPE_AGENT) < k) {
            __builtin_amdgcn_s_sleep(2);
        }
    }
    __syncthreads();
    if (threadIdx.x == 0) __threadfence();   // one acquire: invalidate so new data is fetched
    __syncthreads();
}

// Recompute predicted positions for the whole system into LDS (SoA float4).
__device__ __forceinline__ void predict_to_lds(const float4* __restrict__ locs4,
                                               const float4* __restrict__ vel4,
                                               float4* sx, float4* sy, float4* sz,
                                               int n4, int tid, int nthreads) {
    for (int g = tid; g < n4; g += nthreads) {
        float lo[12], ve[12];
        *(float4*)&lo[0] = locs4[3*g];   *(float4*)&lo[4] = locs4[3*g+1]; *(float4*)&lo[8] = locs4[3*g+2];
        *(float4*)&ve[0] = vel4[3*g];    *(float4*)&ve[4] = vel4[3*g+1];  *(float4*)&ve[8] = vel4[3*g+2];
        float X[4], Y[4], Z[4];
#pragma unroll
        for (int p = 0; p < 4; ++p) {
            float vx = ve[3*p], vy = ve[3*p+1] - 9.8f * DT, vz = ve[3*p+2];
            float vv = sqrtf(vx*vx + vy*vy + vz*vz);
            float s  = fminf(MAX_VEL / (vv + 1e-4f), 1.0f);
            X[p] = lo[3*p]   + DT * vx * s;
            Y[p] = lo[3*p+1] + DT * vy * s;
            Z[p] = lo[3*p+2] + DT * vz * s;
        }
        sx[g] = make_float4(X[0], X[1], X[2], X[3]);
        sy[g] = make_float4(Y[0], Y[1], Y[2], Y[3]);
        sz[g] = make_float4(Z[0], Z[1], Z[2], Z[3]);
    }
}

// rho body (2 particles/wave): writes pre-scaled L = -3C*lam for i0, i0+1 to global.
__device__ __forceinline__ void rho_body2(const float4* sx, const float4* sy, const float4* sz,
                                          float* __restrict__ lam, int n4, int i0, int lane) {
    const float* fx = (const float*)sx; const float* fy = (const float*)sy; const float* fz = (const float*)sz;
    const float xi0 = fx[i0],   yi0 = fy[i0],   zi0 = fz[i0];
    const float xi1 = fx[i0+1], yi1 = fy[i0+1], zi1 = fz[i0+1];
    float S0 = 0.f, S1 = 0.f;
    for (int k = lane; k < n4; k += 64) {
        float4 X = sx[k], Y = sy[k], Z = sz[k];
#pragma unroll
        for (int c = 0; c < 4; ++c) {
            float xj = elem(X,c), yj = elem(Y,c), zj = elem(Z,c);
            {
                float dx = xi0-xj, dy = yi0-yj, dz = zi0-zj;
                float d2 = fmaf(dx,dx,EPS); d2 = fmaf(dy,dy,d2); d2 = fmaf(dz,dz,d2);
                float t  = fmaxf(RADIUS - __builtin_amdgcn_sqrtf(d2), 0.f);
                S0 = fmaf(t*t, t, S0);
            }
            {
                float dx = xi1-xj, dy = yi1-yj, dz = zi1-zj;
                float d2 = fmaf(dx,dx,EPS); d2 = fmaf(dy,dy,d2); d2 = fmaf(dz,dz,d2);
                float t  = fmaxf(RADIUS - __builtin_amdgcn_sqrtf(d2), 0.f);
                S1 = fmaf(t*t, t, S1);
            }
        }
    }
    for (int off = 32; off > 0; off >>= 1) {
        S0 += __shfl_down(S0, off);
        S1 += __shfl_down(S1, off);
    }
    if (lane == 0) {
        const float ts  = RADIUS - __builtin_amdgcn_sqrtf(EPS);  // exact self-term
        const float TS3 = ts*ts*ts;
        const float k3  = 3.f * SPIKY_C * STIFFNESS;             // L = -3C*lam
        lam[i0]   = k3 * (SPIKY_C * (S0 - TS3) - DENSITY_REST);
        lam[i0+1] = k3 * (SPIKY_C * (S1 - TS3) - DENSITY_REST);
    }
}

// delta body (2 particles/wave): writes new positions (and optional final outputs) to global.
__device__ __forceinline__ void delta_body2(const float4* sx, const float4* sy, const float4* sz,
                                            const float4* sl,
                                            float* __restrict__ qx, float* __restrict__ qy, float* __restrict__ qz,
                                            const float* __restrict__ locs, float* __restrict__ out_pred,
                                            float* __restrict__ vnx, float* __restrict__ vny, float* __restrict__ vnz,
                                            int n4, int i0, int lane, bool final_iter) {
    const float* fx = (const float*)sx; const float* fy = (const float*)sy;
    const float* fz = (const float*)sz; const float* fl = (const float*)sl;
    const float xi0 = fx[i0],   yi0 = fy[i0],   zi0 = fz[i0],   L0 = fl[i0];
    const float xi1 = fx[i0+1], yi1 = fy[i0+1], zi1 = fz[i0+1], L1 = fl[i0+1];
    float ax0=0.f, ay0=0.f, az0=0.f, ax1=0.f, ay1=0.f, az1=0.f;
    for (int k = lane; k < n4; k += 64) {
        float4 X = sx[k], Y = sy[k], Z = sz[k], L = sl[k];
#pragma unroll
        for (int c = 0; c < 4; ++c) {
            float xj = elem(X,c), yj = elem(Y,c), zj = elem(Z,c), Lj = elem(L,c);
            {
                float dx = xi0-xj, dy = yi0-yj, dz = zi0-zj;
                float d2 = fmaf(dx,dx,EPS); d2 = fmaf(dy,dy,d2); d2 = fmaf(dz,dz,d2);
                float rinv = __builtin_amdgcn_rsqf(d2);
                float t  = fmaxf(RADIUS - d2*rinv, 0.f);
                float cf = (L0 + Lj) * (t*t) * rinv;
                ax0 = fmaf(cf, dx, ax0); ay0 = fmaf(cf, dy, ay0); az0 = fmaf(cf, dz, az0);
            }
            {
                float dx = xi1-xj, dy = yi1-yj, dz = zi1-zj;
                float d2 = fmaf(dx,dx,EPS); d2 = fmaf(dy,dy,d2); d2 = fmaf(dz,dz,d2);
                float rinv = __builtin_amdgcn_rsqf(d2);
                float t  = fmaxf(RADIUS - d2*rinv, 0.f);
                float cf = (L1 + Lj) * (t*t) * rinv;
                ax1 = fmaf(cf, dx, ax1); ay1 = fmaf(cf, dy, ay1); az1 = fmaf(cf, dz, az1);
            }
        }
    }
    for (int off = 32; off > 0; off >>= 1) {
        ax0 += __shfl_down(ax0, off); ay0 += __shfl_down(ay0, off); az0 += __shfl_down(az0, off);
        ax1 += __shfl_down(ax1, off); ay1 += __shfl_down(ay1, off); az1 += __shfl_down(az1, off);
    }
    if (lane == 0) {
        float nx0 = xi0+ax0, ny0 = yi0+ay0, nz0 = zi0+az0;
        float nx1 = xi1+ax1, ny1 = yi1+ay1, nz1 = zi1+az1;
        qx[i0] = nx0; qy[i0] = ny0; qz[i0] = nz0;
        qx[i0+1] = nx1; qy[i0+1] = ny1; qz[i0+1] = nz1;
        if (final_iter) {
#pragma unroll
            for (int u = 0; u < 2; ++u) {
                int i = i0 + u;
                float nx_ = u ? nx1 : nx0, ny_ = u ? ny1 : ny0, nz_ = u ? nz1 : nz0;
                out_pred[3*i+0] = nx_; out_pred[3*i+1] = ny_; out_pred[3*i+2] = nz_;
                vnx[i] = (nx_ - locs[3*i+0]) * (1.0f/DT);
                vny[i] = (ny_ - locs[3*i+1]) * (1.0f/DT);
                vnz[i] = (nz_ - locs[3*i+2]) * (1.0f/DT);
            }
        }
    }
}

// One cooperative kernel, relaxed-poll barriers. 256 blocks x 512 thr, 64 KB LDS, 2 blocks/CU.
__global__ __launch_bounds__(512, 4) void k_fused(
        const float* __restrict__ locs, const float* __restrict__ vel,
        float* __restrict__ px, float* __restrict__ py, float* __restrict__ pz,
        float* __restrict__ lam,
        float* __restrict__ vnx, float* __restrict__ vny, float* __restrict__ vnz,
        int* __restrict__ flags,
        float* __restrict__ out, int n) {
    __shared__ float4 smem[4 * N4];   // 64 KB
    float4* sx = smem; float4* sy = smem + N4; float4* sz = smem + 2*N4; float4* sl = smem + 3*N4;
    const int tid = threadIdx.x;
    const int wave = tid >> 6, lane = tid & 63;
    const int i0 = blockIdx.x * 16 + wave * 2;
    const int n4 = n >> 2;
    const int nblocks = gridDim.x;

    // ---- 3 solver iterations; predict folded into iteration 0's staging ----
    for (int it = 0; it < 3; ++it) {
        if (it == 0) {
            predict_to_lds((const float4*)locs, (const float4*)vel, sx, sy, sz, n4, tid, 512);
        } else {
            for (int idx = tid; idx < n4; idx += 512) {
                sx[idx] = ((const float4*)px)[idx];
                sy[idx] = ((const float4*)py)[idx];
                sz[idx] = ((const float4*)pz)[idx];
            }
        }
        __syncthreads();
        rho_body2(sx, sy, sz, lam, n4, i0, lane);
        grid_barrier(flags, 2*it + 1, nblocks);                 // lam ready
        for (int idx = tid; idx < n4; idx += 512) sl[idx] = ((const float4*)lam)[idx];
        __syncthreads();
        delta_body2(sx, sy, sz, sl, px, py, pz, locs, out, vnx, vny, vnz,
                    n4, i0, lane, it == 2);
        grid_barrier(flags, 2*it + 2, nblocks);                 // new positions ready
    }

    // ---- XSPH viscosity: 2 chunks of 48 KB staged into smem ----
    const int n8 = n >> 3;
    float4* cx  = smem;        float4* cy  = smem + n8;     float4* cz  = smem + 2*n8;
    float4* cvx = smem + 3*n8; float4* cvy = smem + 4*n8;   float4* cvz = smem + 5*n8;
    const float xi0 = px[i0],  yi0 = py[i0],  zi0 = pz[i0];
    const float xi1 = px[i0+1], yi1 = py[i0+1], zi1 = pz[i0+1];
    const float vix0 = vnx[i0],   viy0 = vny[i0],   viz0 = vnz[i0];
    const float vix1 = vnx[i0+1], viy1 = vny[i0+1], viz1 = vnz[i0+1];
    float ws0=0.f, ax0=0.f, ay0=0.f, az0=0.f;
    float ws1=0.f, ax1=0.f, ay1=0.f, az1=0.f;
    for (int ch = 0; ch < 2; ++ch) {
        __syncthreads();
        for (int idx = tid; idx < n8; idx += 512) {
            cx[idx]  = ((const float4*)px)[ch*n8+idx];
            cy[idx]  = ((const float4*)py)[ch*n8+idx];
            cz[idx]  = ((const float4*)pz)[ch*n8+idx];
            cvx[idx] = ((const float4*)vnx)[ch*n8+idx];
            cvy[idx] = ((const float4*)vny)[ch*n8+idx];
            cvz[idx] = ((const float4*)vnz)[ch*n8+idx];
        }
        __syncthreads();
        for (int k = lane; k < n8; k += 64) {
            float4 X = cx[k], Y = cy[k], Z = cz[k], VX = cvx[k], VY = cvy[k], VZ = cvz[k];
#pragma unroll
            for (int c = 0; c < 4; ++c) {
                float xj = elem(X,c), yj = elem(Y,c), zj = elem(Z,c);
                float vxj = elem(VX,c), vyj = elem(VY,c), vzj = elem(VZ,c);
                {
                    float dx = xi0-xj, dy = yi0-yj, dz = zi0-zj;
                    float d2 = fmaf(dx,dx,EPS); d2 = fmaf(dy,dy,d2); d2 = fmaf(dz,dz,d2);
                    float t  = fmaxf(RADIUS - __builtin_amdgcn_sqrtf(d2), 0.f);
                    float w  = t*t*t;
                    ws0 += w;
                    ax0 = fmaf(w, vxj, ax0); ay0 = fmaf(w, vyj, ay0); az0 = fmaf(w, vzj, az0);
                }
                {
                    float dx = xi1-xj, dy = yi1-yj, dz = zi1-zj;
                    float d2 = fmaf(dx,dx,EPS); d2 = fmaf(dy,dy,d2); d2 = fmaf(dz,dz,d2);
                    float t  = fmaxf(RADIUS - __builtin_amdgcn_sqrtf(d2), 0.f);
                    float w  = t*t*t;
                    ws1 += w;
                    ax1 = fmaf(w, vxj, ax1); ay1 = fmaf(w, vyj, ay1); az1 = fmaf(w, vzj, az1);
                }
            }
        }
    }
    for (int off = 32; off > 0; off >>= 1) {
        ws0 += __shfl_down(ws0, off); ax0 += __shfl_down(ax0, off);
        ay0 += __shfl_down(ay0, off); az0 += __shfl_down(az0, off);
        ws1 += __shfl_down(ws1, off); ax1 += __shfl_down(ax1, off);
        ay1 += __shfl_down(ay1, off); az1 += __shfl_down(az1, off);
    }
    if (lane == 0) {
        constexpr float K = VISCOSITY * DT / DENSITY_REST;
        const float KC = K * SPIKY_C;   // C folded here
#pragma unroll
        for (int u = 0; u < 2; ++u) {
            int i = i0 + u;
            float vix = (u ? vix1 : vix0), viy = (u ? viy1 : viy0), viz = (u ? viz1 : viz0);
            float sw  = (u ? ws1 : ws0);
            float sax = (u ? ax1 : ax0), say = (u ? ay1 : ay0), saz = (u ? az1 : az0);
            float nvx = vix + KC * (sax - sw * vix);
            float nvy = viy + KC * (say - sw * viy);
            float nvz = viz + KC * (saz - sw * viz);
            float vv = sqrtf(nvx*nvx + nvy*nvy + nvz*nvz);
            float s  = fminf(MAX_VEL / (vv + 1e-4f), 1.0f);
            out[3*n + 3*i + 0] = nvx * s;
            out[3*n + 3*i + 1] = nvy * s;
            out[3*n + 3*i + 2] = nvz * s;
        }
    }
}

extern "C" void kernel_launch(void* const* d_in, const int* in_sizes, int n_in,
                              void* d_out, int out_size, void* d_ws, size_t ws_size,
                              hipStream_t stream) {
    const float* locs = (const float*)d_in[0];
    const float* vel  = (const float*)d_in[1];
    float* out = (float*)d_out;
    int n = in_sizes[0] / 3;

    float* w = (float*)d_ws;
    float* px  = w;        float* py  = px + n;   float* pz  = py + n;
    float* lam = pz + n;
    float* vnx = lam + n;  float* vny = vnx + n;  float* vnz = vny + n;
    int* flags = (int*)(vnz + n);

    int nb = n / 16;   // 256 blocks: 8 waves/block, 2 particles/wave; 2 blocks/CU co-resident

    void* args[] = { (void*)&locs, (void*)&vel, (void*)&px, (void*)&py, (void*)&pz,
                     (void*)&lam, (void*)&vnx, (void*)&vny, (void*)&vnz,
                     (void*)&flags, (void*)&out, (void*)&n };
    hipLaunchCooperativeKernel((const void*)k_fused, dim3(nb), dim3(512), args, 0, stream);
}

// Round 8
// 153.507 us; speedup vs baseline: 1.9033x; 1.2454x over previous
//
#include <hip/hip_runtime.h>
#include <math.h>

#define NMAX 4096
#define N4   (NMAX/4)

// n assumed multiple of 16 (reference: N=4096).

constexpr float RADIUS       = 0.1f;
constexpr float DT           = 1.0f / 60.0f;
constexpr float MAX_VEL      = 3.0f;               // 0.5*0.1/DT
constexpr float VISCOSITY    = 60.0f;
constexpr float DENSITY_REST = 17510.1f;
constexpr float STIFFNESS    = 2.99e-11f;
constexpr float EPS          = 1e-8f;
constexpr float SPIKY_C      = (float)(15.0 / (3.14159265358979323846 * 1e-6)); // 15/(pi*R^6)

#define FLAG_STRIDE 16   // ints; 64 B between flags -> no false sharing

__device__ __forceinline__ float elem(const float4& v, int c) {
    return reinterpret_cast<const float*>(&v)[c];
}

// ---- coherent (LLC / sc1) accessors: agent-scope relaxed atomics, 8 B ----
__device__ __forceinline__ float2 cld2(const float* p) {
    unsigned long long v = __hip_atomic_load((const unsigned long long*)p,
                                             __ATOMIC_RELAXED, __HIP_MEMORY_SCOPE_AGENT);
    union { unsigned long long u; float2 f; } c; c.u = v; return c.f;
}
__device__ __forceinline__ void cst2(float* p, float2 v) {
    union { unsigned long long u; float2 f; } c; c.f = v;
    __hip_atomic_store((unsigned long long*)p, c.u,
                       __ATOMIC_RELAXED, __HIP_MEMORY_SCOPE_AGENT);
}

// Fence-free grid barrier. Correctness: __syncthreads() hardware-drains every
// wave's outstanding (sc1, LLC-coherent) stores before s_barrier, so all of this
// block's data stores are globally visible BEFORE the flag store issues. No
// buffer_wbl2/inv cache walks anywhere.
// Sense k monotone 1..6 per launch; ws poison 0xAAAAAAAA < k (signed) -> no init.
__device__ __forceinline__ void grid_barrier(int* __restrict__ flags, int k, int nblocks) {
    __syncthreads();
    if (threadIdx.x == 0)
        __hip_atomic_store(&flags[blockIdx.x * FLAG_STRIDE], k,
                           __ATOMIC_RELAXED, __HIP_MEMORY_SCOPE_AGENT);
    for (int t = threadIdx.x; t < nblocks; t += (int)blockDim.x)
        while (__hip_atomic_load(&flags[t * FLAG_STRIDE],
                                 __ATOMIC_RELAXED, __HIP_MEMORY_SCOPE_AGENT) < k)
            __builtin_amdgcn_s_sleep(2);
    __syncthreads();
}

// Recompute predicted positions for the whole system into LDS (SoA float4).
__device__ __forceinline__ void predict_to_lds(const float4* __restrict__ locs4,
                                               const float4* __restrict__ vel4,
                                               float4* sx, float4* sy, float4* sz,
                                               int n4, int tid, int nthreads) {
    for (int g = tid; g < n4; g += nthreads) {
        float lo[12], ve[12];
        *(float4*)&lo[0] = locs4[3*g];   *(float4*)&lo[4] = locs4[3*g+1]; *(float4*)&lo[8] = locs4[3*g+2];
        *(float4*)&ve[0] = vel4[3*g];    *(float4*)&ve[4] = vel4[3*g+1];  *(float4*)&ve[8] = vel4[3*g+2];
        float X[4], Y[4], Z[4];
#pragma unroll
        for (int p = 0; p < 4; ++p) {
            float vx = ve[3*p], vy = ve[3*p+1] - 9.8f * DT, vz = ve[3*p+2];
            float vv = sqrtf(vx*vx + vy*vy + vz*vz);
            float s  = fminf(MAX_VEL / (vv + 1e-4f), 1.0f);
            X[p] = lo[3*p]   + DT * vx * s;
            Y[p] = lo[3*p+1] + DT * vy * s;
            Z[p] = lo[3*p+2] + DT * vz * s;
        }
        sx[g] = make_float4(X[0], X[1], X[2], X[3]);
        sy[g] = make_float4(Y[0], Y[1], Y[2], Y[3]);
        sz[g] = make_float4(Z[0], Z[1], Z[2], Z[3]);
    }
}

// rho body (2 particles/wave): coherent-writes pre-scaled L = -3C*lam for i0,i0+1.
__device__ __forceinline__ void rho_body2(const float4* sx, const float4* sy, const float4* sz,
                                          float* __restrict__ lam, int n4, int i0, int lane) {
    const float* fx = (const float*)sx; const float* fy = (const float*)sy; const float* fz = (const float*)sz;
    const float xi0 = fx[i0],   yi0 = fy[i0],   zi0 = fz[i0];
    const float xi1 = fx[i0+1], yi1 = fy[i0+1], zi1 = fz[i0+1];
    float S0 = 0.f, S1 = 0.f;
    for (int k = lane; k < n4; k += 64) {
        float4 X = sx[k], Y = sy[k], Z = sz[k];
#pragma unroll
        for (int c = 0; c < 4; ++c) {
            float xj = elem(X,c), yj = elem(Y,c), zj = elem(Z,c);
            {
                float dx = xi0-xj, dy = yi0-yj, dz = zi0-zj;
                float d2 = fmaf(dx,dx,EPS); d2 = fmaf(dy,dy,d2); d2 = fmaf(dz,dz,d2);
                float t  = fmaxf(RADIUS - __builtin_amdgcn_sqrtf(d2), 0.f);
                S0 = fmaf(t*t, t, S0);
            }
            {
                float dx = xi1-xj, dy = yi1-yj, dz = zi1-zj;
                float d2 = fmaf(dx,dx,EPS); d2 = fmaf(dy,dy,d2); d2 = fmaf(dz,dz,d2);
                float t  = fmaxf(RADIUS - __builtin_amdgcn_sqrtf(d2), 0.f);
                S1 = fmaf(t*t, t, S1);
            }
        }
    }
    for (int off = 32; off > 0; off >>= 1) {
        S0 += __shfl_down(S0, off);
        S1 += __shfl_down(S1, off);
    }
    if (lane == 0) {
        const float ts  = RADIUS - __builtin_amdgcn_sqrtf(EPS);  // exact self-term
        const float TS3 = ts*ts*ts;
        const float k3  = 3.f * SPIKY_C * STIFFNESS;             // L = -3C*lam
        cst2(&lam[i0], make_float2(k3 * (SPIKY_C * (S0 - TS3) - DENSITY_REST),
                                   k3 * (SPIKY_C * (S1 - TS3) - DENSITY_REST)));
    }
}

// delta body (2 particles/wave): coherent-writes new positions (+ final outputs).
__device__ __forceinline__ void delta_body2(const float4* sx, const float4* sy, const float4* sz,
                                            const float4* sl,
                                            float* __restrict__ qx, float* __restrict__ qy, float* __restrict__ qz,
                                            const float* __restrict__ locs, float* __restrict__ out_pred,
                                            float* __restrict__ vnx, float* __restrict__ vny, float* __restrict__ vnz,
                                            int n4, int i0, int lane, bool final_iter) {
    const float* fx = (const float*)sx; const float* fy = (const float*)sy;
    const float* fz = (const float*)sz; const float* fl = (const float*)sl;
    const float xi0 = fx[i0],   yi0 = fy[i0],   zi0 = fz[i0],   L0 = fl[i0];
    const float xi1 = fx[i0+1], yi1 = fy[i0+1], zi1 = fz[i0+1], L1 = fl[i0+1];
    float ax0=0.f, ay0=0.f, az0=0.f, ax1=0.f, ay1=0.f, az1=0.f;
    for (int k = lane; k < n4; k += 64) {
        float4 X = sx[k], Y = sy[k], Z = sz[k], L = sl[k];
#pragma unroll
        for (int c = 0; c < 4; ++c) {
            float xj = elem(X,c), yj = elem(Y,c), zj = elem(Z,c), Lj = elem(L,c);
            {
                float dx = xi0-xj, dy = yi0-yj, dz = zi0-zj;
                float d2 = fmaf(dx,dx,EPS); d2 = fmaf(dy,dy,d2); d2 = fmaf(dz,dz,d2);
                float rinv = __builtin_amdgcn_rsqf(d2);
                float t  = fmaxf(RADIUS - d2*rinv, 0.f);
                float cf = (L0 + Lj) * (t*t) * rinv;
                ax0 = fmaf(cf, dx, ax0); ay0 = fmaf(cf, dy, ay0); az0 = fmaf(cf, dz, az0);
            }
            {
                float dx = xi1-xj, dy = yi1-yj, dz = zi1-zj;
                float d2 = fmaf(dx,dx,EPS); d2 = fmaf(dy,dy,d2); d2 = fmaf(dz,dz,d2);
                float rinv = __builtin_amdgcn_rsqf(d2);
                float t  = fmaxf(RADIUS - d2*rinv, 0.f);
                float cf = (L1 + Lj) * (t*t) * rinv;
                ax1 = fmaf(cf, dx, ax1); ay1 = fmaf(cf, dy, ay1); az1 = fmaf(cf, dz, az1);
            }
        }
    }
    for (int off = 32; off > 0; off >>= 1) {
        ax0 += __shfl_down(ax0, off); ay0 += __shfl_down(ay0, off); az0 += __shfl_down(az0, off);
        ax1 += __shfl_down(ax1, off); ay1 += __shfl_down(ay1, off); az1 += __shfl_down(az1, off);
    }
    if (lane == 0) {
        float nx0 = xi0+ax0, ny0 = yi0+ay0, nz0 = zi0+az0;
        float nx1 = xi1+ax1, ny1 = yi1+ay1, nz1 = zi1+az1;
        cst2(&qx[i0], make_float2(nx0, nx1));
        cst2(&qy[i0], make_float2(ny0, ny1));
        cst2(&qz[i0], make_float2(nz0, nz1));
        if (final_iter) {
            // pred -> out (host-read only: plain stores OK, flushed at kernel end)
            out_pred[3*i0+0] = nx0; out_pred[3*i0+1] = ny0; out_pred[3*i0+2] = nz0;
            out_pred[3*i0+3] = nx1; out_pred[3*i0+4] = ny1; out_pred[3*i0+5] = nz1;
            // new_vel -> vn arrays (cross-block read in visc: coherent stores)
            cst2(&vnx[i0], make_float2((nx0 - locs[3*i0+0]) * (1.0f/DT),
                                       (nx1 - locs[3*i0+3]) * (1.0f/DT)));
            cst2(&vny[i0], make_float2((ny0 - locs[3*i0+1]) * (1.0f/DT),
                                       (ny1 - locs[3*i0+4]) * (1.0f/DT)));
            cst2(&vnz[i0], make_float2((nz0 - locs[3*i0+2]) * (1.0f/DT),
                                       (nz1 - locs[3*i0+5]) * (1.0f/DT)));
        }
    }
}

// One cooperative kernel, fence-free barriers. 256 blocks x 512 thr, 64 KB LDS, 2 blocks/CU.
__global__ __launch_bounds__(512, 4) void k_fused(
        const float* __restrict__ locs, const float* __restrict__ vel,
        float* __restrict__ px, float* __restrict__ py, float* __restrict__ pz,
        float* __restrict__ lam,
        float* __restrict__ vnx, float* __restrict__ vny, float* __restrict__ vnz,
        int* __restrict__ flags,
        float* __restrict__ out, int n) {
    __shared__ float4 smem[4 * N4];   // 64 KB
    float4* sx = smem; float4* sy = smem + N4; float4* sz = smem + 2*N4; float4* sl = smem + 3*N4;
    const int tid = threadIdx.x;
    const int wave = tid >> 6, lane = tid & 63;
    const int i0 = blockIdx.x * 16 + wave * 2;
    const int n4 = n >> 2;
    const int n2 = n >> 1;
    const int nblocks = gridDim.x;

    // ---- 3 solver iterations; predict folded into iteration 0's staging ----
    for (int it = 0; it < 3; ++it) {
        if (it == 0) {
            predict_to_lds((const float4*)locs, (const float4*)vel, sx, sy, sz, n4, tid, 512);
        } else {
            for (int idx = tid; idx < n2; idx += 512) {   // coherent 8B staging
                ((float2*)sx)[idx] = cld2(px + 2*idx);
                ((float2*)sy)[idx] = cld2(py + 2*idx);
                ((float2*)sz)[idx] = cld2(pz + 2*idx);
            }
        }
        __syncthreads();
        rho_body2(sx, sy, sz, lam, n4, i0, lane);
        grid_barrier(flags, 2*it + 1, nblocks);                 // lam ready
        for (int idx = tid; idx < n2; idx += 512)
            ((float2*)sl)[idx] = cld2(lam + 2*idx);
        __syncthreads();
        delta_body2(sx, sy, sz, sl, px, py, pz, locs, out, vnx, vny, vnz,
                    n4, i0, lane, it == 2);
        grid_barrier(flags, 2*it + 2, nblocks);                 // new positions ready
    }

    // ---- XSPH viscosity: 2 chunks of 48 KB staged coherently into smem ----
    const int n8 = n >> 3;                 // float4 per chunk array
    const int c2 = n >> 2;                 // float2 per chunk array
    float4* cx  = smem;        float4* cy  = smem + n8;     float4* cz  = smem + 2*n8;
    float4* cvx = smem + 3*n8; float4* cvy = smem + 4*n8;   float4* cvz = smem + 5*n8;
    float2 XI = cld2(&px[i0]), YI = cld2(&py[i0]), ZI = cld2(&pz[i0]);
    float2 VXI = cld2(&vnx[i0]), VYI = cld2(&vny[i0]), VZI = cld2(&vnz[i0]);
    const float xi0 = XI.x,  yi0 = YI.x,  zi0 = ZI.x;
    const float xi1 = XI.y,  yi1 = YI.y,  zi1 = ZI.y;
    const float vix0 = VXI.x, viy0 = VYI.x, viz0 = VZI.x;
    const float vix1 = VXI.y, viy1 = VYI.y, viz1 = VZI.y;
    float ws0=0.f, ax0=0.f, ay0=0.f, az0=0.f;
    float ws1=0.f, ax1=0.f, ay1=0.f, az1=0.f;
    for (int ch = 0; ch < 2; ++ch) {
        __syncthreads();
        for (int idx = tid; idx < c2; idx += 512) {
            int g = ch*n2 + 2*idx;   // float offset within arrays
            ((float2*)cx)[idx]  = cld2(px + g);
            ((float2*)cy)[idx]  = cld2(py + g);
            ((float2*)cz)[idx]  = cld2(pz + g);
            ((float2*)cvx)[idx] = cld2(vnx + g);
            ((float2*)cvy)[idx] = cld2(vny + g);
            ((float2*)cvz)[idx] = cld2(vnz + g);
        }
        __syncthreads();
        for (int k = lane; k < n8; k += 64) {
            float4 X = cx[k], Y = cy[k], Z = cz[k], VX = cvx[k], VY = cvy[k], VZ = cvz[k];
#pragma unroll
            for (int c = 0; c < 4; ++c) {
                float xj = elem(X,c), yj = elem(Y,c), zj = elem(Z,c);
                float vxj = elem(VX,c), vyj = elem(VY,c), vzj = elem(VZ,c);
                {
                    float dx = xi0-xj, dy = yi0-yj, dz = zi0-zj;
                    float d2 = fmaf(dx,dx,EPS); d2 = fmaf(dy,dy,d2); d2 = fmaf(dz,dz,d2);
                    float t  = fmaxf(RADIUS - __builtin_amdgcn_sqrtf(d2), 0.f);
                    float w  = t*t*t;
                    ws0 += w;
                    ax0 = fmaf(w, vxj, ax0); ay0 = fmaf(w, vyj, ay0); az0 = fmaf(w, vzj, az0);
                }
                {
                    float dx = xi1-xj, dy = yi1-yj, dz = zi1-zj;
                    float d2 = fmaf(dx,dx,EPS); d2 = fmaf(dy,dy,d2); d2 = fmaf(dz,dz,d2);
                    float t  = fmaxf(RADIUS - __builtin_amdgcn_sqrtf(d2), 0.f);
                    float w  = t*t*t;
                    ws1 += w;
                    ax1 = fmaf(w, vxj, ax1); ay1 = fmaf(w, vyj, ay1); az1 = fmaf(w, vzj, az1);
                }
            }
        }
    }
    for (int off = 32; off > 0; off >>= 1) {
        ws0 += __shfl_down(ws0, off); ax0 += __shfl_down(ax0, off);
        ay0 += __shfl_down(ay0, off); az0 += __shfl_down(az0, off);
        ws1 += __shfl_down(ws1, off); ax1 += __shfl_down(ax1, off);
        ay1 += __shfl_down(ay1, off); az1 += __shfl_down(az1, off);
    }
    if (lane == 0) {
        constexpr float K = VISCOSITY * DT / DENSITY_REST;
        const float KC = K * SPIKY_C;   // C folded here
#pragma unroll
        for (int u = 0; u < 2; ++u) {
            int i = i0 + u;
            float vix = (u ? vix1 : vix0), viy = (u ? viy1 : viy0), viz = (u ? viz1 : viz0);
            float sw  = (u ? ws1 : ws0);
            float sax = (u ? ax1 : ax0), say = (u ? ay1 : ay0), saz = (u ? az1 : az0);
            float nvx = vix + KC * (sax - sw * vix);
            float nvy = viy + KC * (say - sw * viy);
            float nvz = viz + KC * (saz - sw * viz);
            float vv = sqrtf(nvx*nvx + nvy*nvy + nvz*nvz);
            float s  = fminf(MAX_VEL / (vv + 1e-4f), 1.0f);
            out[3*n + 3*i + 0] = nvx * s;
            out[3*n + 3*i + 1] = nvy * s;
            out[3*n + 3*i + 2] = nvz * s;
        }
    }
}

extern "C" void kernel_launch(void* const* d_in, const int* in_sizes, int n_in,
                              void* d_out, int out_size, void* d_ws, size_t ws_size,
                              hipStream_t stream) {
    const float* locs = (const float*)d_in[0];
    const float* vel  = (const float*)d_in[1];
    float* out = (float*)d_out;
    int n = in_sizes[0] / 3;

    float* w = (float*)d_ws;
    float* px  = w;        float* py  = px + n;   float* pz  = py + n;
    float* lam = pz + n;
    float* vnx = lam + n;  float* vny = vnx + n;  float* vnz = vny + n;
    int* flags = (int*)(vnz + n);

    int nb = n / 16;   // 256 blocks: 8 waves/block, 2 particles/wave; 2 blocks/CU co-resident

    void* args[] = { (void*)&locs, (void*)&vel, (void*)&px, (void*)&py, (void*)&pz,
                     (void*)&lam, (void*)&vnx, (void*)&vny, (void*)&vnz,
                     (void*)&flags, (void*)&out, (void*)&n };
    hipLaunchCooperativeKernel((const void*)k_fused, dim3(nb), dim3(512), args, 0, stream);
}